// Round 6
// baseline (362.313 us; speedup 1.0000x reference)
//
#include <hip/hip_runtime.h>

#define HWD 256
#define HW2 (HWD * HWD)        // 65536 spatial positions per plane
#define NB 8                   // batch
#define NC 64                  // channels
#define PLANE4 (HW2 / 4)       // 16384 float4 per spatial plane

typedef float floatx4 __attribute__((ext_vector_type(4)));

// ---------------------------------------------------------------------------
// Kernel 1: channel-wise L1 norms.
// ROUND-5 THEORY: carry x2 through L3 to blend. x1+x2 (268MB) never fit MALL
// (256MB) -> that was the 50%-hit thrash of R0-R3. x2 alone (134MB) fits.
// So: x1 read NON-TEMPORAL (stream, don't allocate, don't evict anything),
// x2 read NORMAL (pure cold-miss allocate stream -> full-speed like m13,
// lines stay resident). Blend then hits L3 for all of x2.
// NT-everything (R5) was the first norms win (97 -> <78us); keeping x1 NT
// preserves it, and x2-normal is a pure miss stream into a quiet MALL.
// grid = 2 inputs x 8 batch x 256 tiles = 4096 blocks.
// ---------------------------------------------------------------------------
__global__ __launch_bounds__(256, 8)
void norms_kernel(const float* __restrict__ x1,
                  const float* __restrict__ x2,
                  float* __restrict__ n1,
                  float* __restrict__ n2) {
    const int t = threadIdx.x;
    const int s = t & 63;            // spatial float4 within tile
    const int g = t >> 6;            // wave id = channel group (0..3)
    const int blk = blockIdx.x;
    const int tile = blk & 255;      // 256 tiles of 64 float4 per plane
    const int b = (blk >> 8) & 7;
    const int inp = blk >> 11;       // 0 -> x1 (NT), 1 -> x2 (cached)

    const int p = tile * 64 + s;     // float4 index within plane
    const size_t off = ((size_t)(b * NC + g * 16)) * PLANE4 + p;

    float4 a = make_float4(0.f, 0.f, 0.f, 0.f);

    if (inp == 0) {
        const floatx4* xv = (const floatx4*)x1 + off;
#pragma unroll
        for (int c = 0; c < 16; ++c) {
            floatx4 v = __builtin_nontemporal_load(xv + (size_t)c * PLANE4);
            a.x += fabsf(v.x); a.y += fabsf(v.y);
            a.z += fabsf(v.z); a.w += fabsf(v.w);
        }
    } else {
        const float4* xv = (const float4*)x2 + off;
#pragma unroll
        for (int c = 0; c < 16; ++c) {
            float4 v = xv[(size_t)c * PLANE4];     // normal: allocate in MALL
            a.x += fabsf(v.x); a.y += fabsf(v.y);
            a.z += fabsf(v.z); a.w += fabsf(v.w);
        }
    }

    __shared__ float4 red[4][64];
    red[g][s] = a;
    __syncthreads();

    if (g == 0) {
        float4 r0 = red[0][s], r1 = red[1][s], r2 = red[2][s], r3 = red[3][s];
        float4 o;
        o.x = (r0.x + r1.x) + (r2.x + r3.x);
        o.y = (r0.y + r1.y) + (r2.y + r3.y);
        o.z = (r0.z + r1.z) + (r2.z + r3.z);
        o.w = (r0.w + r1.w) + (r2.w + r3.w);
        float* n = inp ? n2 : n1;
        ((float4*)n)[(size_t)b * PLANE4 + p] = o;
    }
}

// ---------------------------------------------------------------------------
// Kernel 2: 3x3 conv (zero pad) + bias on n1,n2; emit r = c1/(c1+c2).
// float4-ized, L2/L3-resident working set (6MB -> leaves x2 untouched).
// grid: NB * HW2 / 4 / 256 = 512 blocks  (unchanged)
// ---------------------------------------------------------------------------
__global__ void conv_ratio_kernel(const float* __restrict__ n1,
                                  const float* __restrict__ n2,
                                  const float* __restrict__ w,
                                  const float* __restrict__ bias,
                                  float* __restrict__ r) {
    int t = blockIdx.x * blockDim.x + threadIdx.x;   // [0, NB*HW2/4)
    int b = t >> 14;                                  // HW2/4 = 16384 per batch
    int sp = t & ((HW2 / 4) - 1);
    int y = sp >> 6;                                  // 64 float4 per row
    int x0 = (sp & 63) << 2;                          // leftmost pixel of the 4

    const float* p1 = n1 + (size_t)b * HW2;
    const float* p2 = n2 + (size_t)b * HW2;

    float o1[4] = {0.f, 0.f, 0.f, 0.f};
    float o2[4] = {0.f, 0.f, 0.f, 0.f};

#pragma unroll
    for (int dy = -1; dy <= 1; ++dy) {
        int yy = y + dy;
        if (yy < 0 || yy >= HWD) continue;   // zero pad
        const float* r1 = p1 + yy * HWD;
        const float* r2 = p2 + yy * HWD;
        float4 m1 = *(const float4*)(r1 + x0);
        float4 m2 = *(const float4*)(r2 + x0);
        float e1[6], e2[6];
        e1[0] = (x0 > 0) ? r1[x0 - 1] : 0.f;
        e2[0] = (x0 > 0) ? r2[x0 - 1] : 0.f;
        e1[1] = m1.x; e1[2] = m1.y; e1[3] = m1.z; e1[4] = m1.w;
        e2[1] = m2.x; e2[2] = m2.y; e2[3] = m2.z; e2[4] = m2.w;
        e1[5] = (x0 + 4 < HWD) ? r1[x0 + 4] : 0.f;
        e2[5] = (x0 + 4 < HWD) ? r2[x0 + 4] : 0.f;
        const float* wr = w + (dy + 1) * 3;
#pragma unroll
        for (int j = 0; j < 4; ++j) {
#pragma unroll
            for (int k = 0; k < 3; ++k) {
                o1[j] += wr[k] * e1[j + k];
                o2[j] += wr[k] * e2[j + k];
            }
        }
    }

    float bv = bias[0];
    float4 out;
    { float c1 = o1[0] + bv, c2 = o2[0] + bv; out.x = c1 / (c1 + c2); }
    { float c1 = o1[1] + bv, c2 = o2[1] + bv; out.y = c1 / (c1 + c2); }
    { float c1 = o1[2] + bv, c2 = o2[2] + bv; out.z = c1 / (c1 + c2); }
    { float c1 = o1[3] + bv, c2 = o2[3] + bv; out.w = c1 / (c1 + c2); }
    ((float4*)r)[t] = out;
}

// ---------------------------------------------------------------------------
// Kernel 3: out = x1 * r + x2 * (1 - r), linear float4 streaming sweep.
// x1: NT load (true HBM stream). x2: NORMAL load -> L3 hits (carried from
// norms). r: normal (L2-hot, each element re-read 64x across channels).
// NT stores: output never evicts x2.
// grid: 2048 blocks x 256 threads x 16 iters.
// ---------------------------------------------------------------------------
#define BLEND_BLOCKS 2048
#define BLEND_STRIDE ((size_t)BLEND_BLOCKS * 256)   // 524288 threads

__global__ __launch_bounds__(256, 8)
void blend_kernel(const float* __restrict__ x1,
                  const float* __restrict__ x2,
                  const float* __restrict__ r,
                  float* __restrict__ out) {
    size_t idx = (size_t)blockIdx.x * 256 + threadIdx.x;
    const floatx4* x1v = (const floatx4*)x1;
    const float4* x2v = (const float4*)x2;
    const float4* rv4 = (const float4*)r;
    floatx4* ov = (floatx4*)out;

#pragma unroll 1
    for (int k = 0; k < 16; ++k) {
        size_t i = idx + (size_t)k * BLEND_STRIDE;
        int b = (int)(i >> 20);              // NC*PLANE4 = 2^20 float4/batch
        int p = (int)(i & (PLANE4 - 1));
        floatx4 v1 = __builtin_nontemporal_load(x1v + i);
        float4 v2 = x2v[i];                  // L3 hit (carried from norms)
        float4 rv = rv4[((size_t)b << 14) + p];
        floatx4 o;
        o.x = v1.x * rv.x + v2.x * (1.f - rv.x);
        o.y = v1.y * rv.y + v2.y * (1.f - rv.y);
        o.z = v1.z * rv.z + v2.z * (1.f - rv.z);
        o.w = v1.w * rv.w + v2.w * (1.f - rv.w);
        __builtin_nontemporal_store(o, ov + i);
    }
}

extern "C" void kernel_launch(void* const* d_in, const int* in_sizes, int n_in,
                              void* d_out, int out_size, void* d_ws, size_t ws_size,
                              hipStream_t stream) {
    const float* x1 = (const float*)d_in[0];
    const float* x2 = (const float*)d_in[1];
    const float* w  = (const float*)d_in[2];
    const float* bv = (const float*)d_in[3];
    float* out = (float*)d_out;

    // workspace layout: n1 | n2 | r, each NB*HW2 floats (2 MiB)
    float* n1 = (float*)d_ws;
    float* n2 = n1 + (size_t)NB * HW2;
    float* r  = n2 + (size_t)NB * HW2;

    const int block = 256;

    norms_kernel<<<2 * NB * 256, block, 0, stream>>>(x1, x2, n1, n2);
    conv_ratio_kernel<<<NB * HW2 / 4 / block, block, 0, stream>>>(n1, n2, w, bv, r);
    blend_kernel<<<BLEND_BLOCKS, block, 0, stream>>>(x1, x2, r, out);
}